// Round 9
// baseline (289.057 us; speedup 1.0000x reference)
//
#include <hip/hip_runtime.h>

#define T_STEPS 512
#define BATCH   2048
#define HID     64
#define IN0     8
#define SPW     16
#define NPAIR   (BATCH / SPW)        // 128 producer/consumer pairs
#define NBLK    (BATCH / SPW)
#define SS      8                    // steps per publish group
#define NSS     (T_STEPS / SS)       // 64 groups
#define RSLOT   32                   // H0 ring depth in steps (64 KB/pair)
#define RING_U64 (RSLOT * 256)       // u64 words per pair ring
#define DATA_OFF 65536               // ring region offset in d_ws (flags first)
#define FLAG_STRIDE 256              // bytes per pair flag record
#define WS_NEEDED ((size_t)DATA_OFF + (size_t)NPAIR * (RING_U64 * 8))
#define SPIN_CAP  (1 << 18)          // bounded spin: ~30 ms max, never hangs

typedef _Float16 h2 __attribute__((ext_vector_type(2)));
typedef _Float16 h4 __attribute__((ext_vector_type(4)));
typedef _Float16 h8 __attribute__((ext_vector_type(8)));
typedef float    f4 __attribute__((ext_vector_type(4)));
typedef unsigned long long u64;

#define MFMA(a, b, c) __builtin_amdgcn_mfma_f32_16x16x32_f16((a), (b), (c), 0, 0, 0)

union F8  { h8 v; h2 p[4]; };
union H4U { h4 v; h2 p[2]; };
union H8U { h8 v; h4 h[2]; };
union H4B { h4 v; u64 b; };

__device__ __forceinline__ h2 pkrtz(float a, float b) {
    return __builtin_bit_cast(h2, __builtin_amdgcn_cvt_pkrtz(a, b));
}

// tanh(x) = 1 - 2/(exp(2x)+1); saturates correctly at +/-inf.
__device__ __forceinline__ float tanh_fast(float x) {
    float e = __builtin_amdgcn_exp2f(x * 2.885390081777927f);
    return 1.0f - 2.0f * __builtin_amdgcn_rcpf(e + 1.0f);
}

__device__ __forceinline__ h8 load_frag_f16(const float* Wrow) {
    const float4* p = (const float4*)Wrow;
    float4 a = p[0], b = p[1];
    F8 f; f.p[0] = pkrtz(a.x, a.y); f.p[1] = pkrtz(a.z, a.w);
          f.p[2] = pkrtz(b.x, b.y); f.p[3] = pkrtz(b.z, b.w);
    return f.v;
}

// Barrier draining ONLY lgkmcnt (LDS); globals stay in flight.
#define LDS_BARRIER() asm volatile("s_waitcnt lgkmcnt(0)\n\ts_barrier" ::: "memory")

#define ALOAD(p)     __hip_atomic_load((p),  __ATOMIC_RELAXED, __HIP_MEMORY_SCOPE_AGENT)
#define ASTORE(p, v) __hip_atomic_store((p), (v), __ATOMIC_RELAXED, __HIP_MEMORY_SCOPE_AGENT)

// ============================================================================
// Decoupled design: blocks 0..127 = layer-0 producers (4 waves, private
// barrier domain), blocks 128..255 = layer-1 consumers. Cross-layer H0 via
// global ring + group flags (agent-scope atomics). All spins BOUNDED.
// ============================================================================
__global__ __launch_bounds__(256, 1)
void rnn2_decoup(const float* __restrict__ x,
                 const float* __restrict__ Wih0, const float* __restrict__ Whh0,
                 const float* __restrict__ bih0, const float* __restrict__ bhh0,
                 const float* __restrict__ Wih1, const float* __restrict__ Whh1,
                 const float* __restrict__ bih1, const float* __restrict__ bhh1,
                 const float* __restrict__ fcw,  const float* __restrict__ fcb,
                 float* __restrict__ out, void* __restrict__ ws) {
    const int tid  = threadIdx.x;
    const int mt   = tid >> 6;       // wave = m-tile (H rows 16mt..16mt+15)
    const int lane = tid & 63;
    const int n    = lane & 15;      // B/C column = sequence
    const int q    = lane >> 4;
    const bool isL0 = (blockIdx.x < NPAIR);
    const int pair  = isL0 ? blockIdx.x : blockIdx.x - NPAIR;
    const int bseq  = pair * SPW;

    int* prodp = (int*)((char*)ws + (size_t)pair * FLAG_STRIDE);
    int* consp = (int*)((char*)ws + (size_t)pair * FLAG_STRIDE + 128);
    u64* ring  = (u64*)((char*)ws + DATA_OFF + (size_t)pair * (RING_U64 * 8));

    // Per-block H exchange (R5 layout, measured conflict-free):
    //   write: [bf][4mt+q][n] h4;  read: 4x h4 at chunks {2q,2q+1,8+2q,9+2q}
    __shared__ __align__(16) h4 Hc[2][16][16];
    __shared__ float red[4][SPW];

    const int wc = 4 * mt + q;
    const f4 zero = {0.f, 0.f, 0.f, 0.f};
    const h2 z2 = pkrtz(0.f, 0.f);
    const int row = 16 * mt + n;
    const float fcb0 = fcb[0];

    if (isL0) {
        // ================= layer-0 producer block =================
        h8 wa[2], wi0;
        f4 biasc;
        #pragma unroll
        for (int kt = 0; kt < 2; ++kt)
            wa[kt] = load_frag_f16(Whh0 + row * HID + 32 * kt + 8 * q);
        {
            const float2 ww = *(const float2*)(Wih0 + row * IN0 + 2 * q);
            F8 f; f.p[0] = pkrtz(ww.x, ww.y); f.p[1] = z2; f.p[2] = z2; f.p[3] = z2;
            wi0 = f.v;
        }
        #pragma unroll
        for (int r = 0; r < 4; ++r) {
            const int i = 16 * mt + 4 * q + r;
            biasc[r] = bih0[i] + bhh0[i];
        }

        const float* xrow = x + ((size_t)(bseq + n) * T_STEPS) * IN0 + 2 * q;
        h8 h0f[2] = {};
        f4 a0x;
        float2 xb[SS];
        {
            const float2 x0 = *(const float2*)xrow;
            F8 xf; xf.p[0] = pkrtz(x0.x, x0.y); xf.p[1] = z2; xf.p[2] = z2; xf.p[3] = z2;
            a0x = MFMA(wi0, xf.v, biasc);
            #pragma unroll
            for (int i = 0; i < SS; ++i) {
                int tn = i + 1; if (tn > T_STEPS - 1) tn = T_STEPS - 1;
                xb[i] = *(const float2*)(xrow + tn * IN0);
            }
        }

        for (int s = 0; s < NSS; ++s) {
            // ring back-pressure (bounded): L1 lags ~2 groups; rarely spins.
            if (lane == 0) {
                int it = 0;
                while (ALOAD(consp) < 8 * s - (RSLOT - SS) && it++ < SPIN_CAP)
                    __builtin_amdgcn_s_sleep(2);
            }
            #pragma unroll
            for (int i = 0; i < SS; ++i) {
                const int t = SS * s + i;
                const int bf = i & 1;
                f4 p0 = MFMA(wa[0], h0f[0], a0x);
                f4 p1 = MFMA(wa[1], h0f[1], zero);
                const f4 a0 = p0 + p1;
                H4U u;
                u.p[0] = pkrtz(tanh_fast(a0[0]), tanh_fast(a0[1]));
                u.p[1] = pkrtz(tanh_fast(a0[2]), tanh_fast(a0[3]));
                Hc[bf][wc][n] = u.v;
                // publish to global ring (off-chain)
                { H4B bb; bb.v = u.v;
                  ASTORE(ring + (size_t)(t & (RSLOT - 1)) * 256 + wc * 16 + n, bb.b); }
                // a0x(t+1) + rolling x refill — off the chain
                F8 xf; xf.p[0] = pkrtz(xb[i].x, xb[i].y);
                xf.p[1] = z2; xf.p[2] = z2; xf.p[3] = z2;
                a0x = MFMA(wi0, xf.v, biasc);
                int tn = t + 1 + SS; if (tn > T_STEPS - 1) tn = T_STEPS - 1;
                xb[i] = *(const float2*)(xrow + tn * IN0);

                if (i == SS - 1) asm volatile("s_waitcnt vmcnt(0)" ::: "memory");
                LDS_BARRIER();
                if (i == SS - 1 && mt == 0 && lane == 0)
                    ASTORE(prodp, t + 1);   // all 4 waves drained pre-barrier
                H8U b0, b1;
                b0.h[0] = Hc[bf][2 * q][n];     b0.h[1] = Hc[bf][2 * q + 1][n];
                b1.h[0] = Hc[bf][8 + 2 * q][n]; b1.h[1] = Hc[bf][9 + 2 * q][n];
                h0f[0] = b0.v; h0f[1] = b1.v;
            }
        }
        return;   // out written by L1 blocks
    }

    // ================= layer-1 consumer block =================
    h8 wa[2], wb[2];
    f4 biasc, fcv;
    #pragma unroll
    for (int kt = 0; kt < 2; ++kt) {
        wa[kt] = load_frag_f16(Wih1 + row * HID + 32 * kt + 8 * q);
        wb[kt] = load_frag_f16(Whh1 + row * HID + 32 * kt + 8 * q);
    }
    #pragma unroll
    for (int r = 0; r < 4; ++r) {
        const int i = 16 * mt + 4 * q + r;
        biasc[r] = bih1[i] + bhh1[i];
        fcv[r]   = fcw[i];
    }

    h8 h1f[2] = {};                 // H1(t-1), starts at H1(-1)=0
    f4 th = {0.f, 0.f, 0.f, 0.f};   // tanh(H1(t)) of the last computed step
    h8 pA0[SS], pA1[SS], pB0[SS], pB1[SS];   // prefetched H0 B-frags

    auto spin_prod = [&](int tgt) {
        if (lane == 0) {
            int it = 0;
            while (ALOAD(prodp) < tgt && it++ < SPIN_CAP)
                __builtin_amdgcn_s_sleep(2);
        }
    };
    auto l1_load = [&](h8 (&P0)[SS], h8 (&P1)[SS], int g) {
        #pragma unroll
        for (int i = 0; i < SS; ++i) {
            const u64* rp = ring + (size_t)((g * SS + i) & (RSLOT - 1)) * 256;
            H4B va, vb, vc, vd;
            va.b = ALOAD(rp + (2 * q) * 16 + n);
            vb.b = ALOAD(rp + (2 * q + 1) * 16 + n);
            vc.b = ALOAD(rp + (8 + 2 * q) * 16 + n);
            vd.b = ALOAD(rp + (9 + 2 * q) * 16 + n);
            H8U f0, f1;
            f0.h[0] = va.v; f0.h[1] = vb.v;
            f1.h[0] = vc.v; f1.h[1] = vd.v;
            P0[i] = f0.v; P1[i] = f1.v;
        }
    };
    auto l1_group = [&](h8 (&P0)[SS], h8 (&P1)[SS]) {
        #pragma unroll
        for (int i = 0; i < SS; ++i) {
            const int bf = i & 1;
            // H1(t) = tanh(b1 + Wih1@H0(t) + Whh1@H1(t-1)); H0 from registers
            f4 c0 = MFMA(wa[0], P0[i], biasc);
            f4 c1 = MFMA(wa[1], P1[i], zero);
            f4 c2 = MFMA(wb[0], h1f[0], zero);
            f4 c3 = MFMA(wb[1], h1f[1], zero);
            const f4 a1 = (c0 + c1) + (c2 + c3);
            th[0] = tanh_fast(a1[0]); th[1] = tanh_fast(a1[1]);
            th[2] = tanh_fast(a1[2]); th[3] = tanh_fast(a1[3]);
            H4U u;
            u.p[0] = pkrtz(th[0], th[1]);
            u.p[1] = pkrtz(th[2], th[3]);
            Hc[bf][wc][n] = u.v;
            LDS_BARRIER();
            H8U b0, b1;
            b0.h[0] = Hc[bf][2 * q][n];     b0.h[1] = Hc[bf][2 * q + 1][n];
            b1.h[0] = Hc[bf][8 + 2 * q][n]; b1.h[1] = Hc[bf][9 + 2 * q][n];
            h1f[0] = b0.v; h1f[1] = b1.v;
        }
    };

    spin_prod(SS);
    l1_load(pA0, pA1, 0);
    for (int G2 = 0; G2 < NSS / 2; ++G2) {
        const int g = 2 * G2;
        spin_prod(8 * (g + 2));
        l1_load(pB0, pB1, g + 1);
        l1_group(pA0, pA1);
        if (mt == 0 && lane == 0) ASTORE(consp, 8 * (g + 1));
        if (g + 2 < NSS) {
            spin_prod(8 * (g + 3));
            l1_load(pA0, pA1, g + 2);
        }
        l1_group(pB0, pB1);
        if (mt == 0 && lane == 0) ASTORE(consp, 8 * (g + 2));
    }

    // ---- FC head from th = tanh(H1(511)) rows 16mt+4q+r ----
    float sacc = th[0] * fcv[0] + th[1] * fcv[1] + th[2] * fcv[2] + th[3] * fcv[3];
    sacc += __shfl_xor(sacc, 16, 64);
    sacc += __shfl_xor(sacc, 32, 64);
    if (lane < 16) red[mt][n] = sacc;
    __syncthreads();
    if (tid < SPW)
        out[bseq + tid] = red[0][tid] + red[1][tid] + red[2][tid] + red[3][tid] + fcb0;
}

// ============================================================================
// Fallback: R5 champion (verified 235.4 µs harness / ~175 µs rocprof, 0
// bank conflicts). Launched when ws_size can't hold the ring.
// ============================================================================
__global__ __launch_bounds__(512, 1)
void rnn2_cf(const float* __restrict__ x,
             const float* __restrict__ Wih0, const float* __restrict__ Whh0,
             const float* __restrict__ bih0, const float* __restrict__ bhh0,
             const float* __restrict__ Wih1, const float* __restrict__ Whh1,
             const float* __restrict__ bih1, const float* __restrict__ bhh1,
             const float* __restrict__ fcw,  const float* __restrict__ fcb,
             float* __restrict__ out) {
    const int tid  = threadIdx.x;
    const int w    = tid >> 6;
    const int mt   = w & 3;
    const bool L0  = (w < 4);
    const int lane = tid & 63;
    const int n    = lane & 15;
    const int q    = lane >> 4;
    const int bseq = blockIdx.x * SPW;

    __shared__ __align__(16) h4 H0c[2][16][16];
    __shared__ __align__(16) h4 H1c[2][16][16];
    __shared__ float red[4][SPW];

    const int wc = 4 * mt + q;
    const f4 zero = {0.f, 0.f, 0.f, 0.f};
    const h2 z2 = pkrtz(0.f, 0.f);

    h8 wa[2], wb[2], wi0;
    f4 biasc, fcv;
    const int row = 16 * mt + n;
    if (L0) {
        #pragma unroll
        for (int kt = 0; kt < 2; ++kt)
            wa[kt] = load_frag_f16(Whh0 + row * HID + 32 * kt + 8 * q);
        const float2 ww = *(const float2*)(Wih0 + row * IN0 + 2 * q);
        F8 f; f.p[0] = pkrtz(ww.x, ww.y); f.p[1] = z2; f.p[2] = z2; f.p[3] = z2;
        wi0 = f.v;
        #pragma unroll
        for (int r = 0; r < 4; ++r) {
            const int i = 16 * mt + 4 * q + r;
            biasc[r] = bih0[i] + bhh0[i];
        }
    } else {
        #pragma unroll
        for (int kt = 0; kt < 2; ++kt) {
            wa[kt] = load_frag_f16(Wih1 + row * HID + 32 * kt + 8 * q);
            wb[kt] = load_frag_f16(Whh1 + row * HID + 32 * kt + 8 * q);
        }
        #pragma unroll
        for (int r = 0; r < 4; ++r) {
            const int i = 16 * mt + 4 * q + r;
            biasc[r] = bih1[i] + bhh1[i];
            fcv[r]   = fcw[i];
        }
    }
    const float fcb0 = fcb[0];

    const float* xrow = x + ((size_t)(bseq + n) * T_STEPS) * IN0 + 2 * q;

    h8 h0f[2] = {}, h1f[2] = {};
    f4 a0x;
    float2 xb[SS];
    if (L0) {
        const float2 x0 = *(const float2*)xrow;
        F8 xf; xf.p[0] = pkrtz(x0.x, x0.y); xf.p[1] = z2; xf.p[2] = z2; xf.p[3] = z2;
        a0x = MFMA(wi0, xf.v, biasc);
        #pragma unroll
        for (int i = 0; i < SS; ++i) {
            int tn = i + 1; if (tn > T_STEPS - 1) tn = T_STEPS - 1;
            xb[i] = *(const float2*)(xrow + tn * IN0);
        }
    }

    for (int s = 0; s < NSS; ++s) {
        #pragma unroll
        for (int i = 0; i < SS; ++i) {
            const int t = SS * s + i;
            const int bf = t & 1;
            if (L0) {
                f4 p0 = MFMA(wa[0], h0f[0], a0x);
                f4 p1 = MFMA(wa[1], h0f[1], zero);
                const f4 a0 = p0 + p1;
                H4U u;
                u.p[0] = pkrtz(tanh_fast(a0[0]), tanh_fast(a0[1]));
                u.p[1] = pkrtz(tanh_fast(a0[2]), tanh_fast(a0[3]));
                H0c[bf][wc][n] = u.v;
                F8 xf; xf.p[0] = pkrtz(xb[i].x, xb[i].y);
                xf.p[1] = z2; xf.p[2] = z2; xf.p[3] = z2;
                a0x = MFMA(wi0, xf.v, biasc);
                int tn = t + 1 + SS; if (tn > T_STEPS - 1) tn = T_STEPS - 1;
                xb[i] = *(const float2*)(xrow + tn * IN0);
            } else {
                f4 c0 = MFMA(wa[0], h0f[0], biasc);
                f4 c1 = MFMA(wa[1], h0f[1], zero);
                f4 c2 = MFMA(wb[0], h1f[0], zero);
                f4 c3 = MFMA(wb[1], h1f[1], zero);
                const f4 a1 = (c0 + c1) + (c2 + c3);
                H4U u;
                u.p[0] = pkrtz(tanh_fast(a1[0]), tanh_fast(a1[1]));
                u.p[1] = pkrtz(tanh_fast(a1[2]), tanh_fast(a1[3]));
                if (t == 0) { u.p[0] = z2; u.p[1] = z2; }
                H1c[bf][wc][n] = u.v;
            }
            LDS_BARRIER();
            {
                H8U b0, b1;
                b0.h[0] = H0c[bf][2 * q][n];     b0.h[1] = H0c[bf][2 * q + 1][n];
                b1.h[0] = H0c[bf][8 + 2 * q][n]; b1.h[1] = H0c[bf][9 + 2 * q][n];
                h0f[0] = b0.v; h0f[1] = b1.v;
            }
            if (!L0) {
                H8U b0, b1;
                b0.h[0] = H1c[bf][2 * q][n];     b0.h[1] = H1c[bf][2 * q + 1][n];
                b1.h[0] = H1c[bf][8 + 2 * q][n]; b1.h[1] = H1c[bf][9 + 2 * q][n];
                h1f[0] = b0.v; h1f[1] = b1.v;
            }
        }
    }

    if (!L0) {
        f4 c0 = MFMA(wa[0], h0f[0], biasc);
        f4 c1 = MFMA(wa[1], h0f[1], zero);
        f4 c2 = MFMA(wb[0], h1f[0], zero);
        f4 c3 = MFMA(wb[1], h1f[1], zero);
        const f4 a1 = (c0 + c1) + (c2 + c3);
        float sacc = 0.f;
        #pragma unroll
        for (int r = 0; r < 4; ++r) sacc += fcv[r] * tanh_fast(a1[r]);
        sacc += __shfl_xor(sacc, 16, 64);
        sacc += __shfl_xor(sacc, 32, 64);
        if (lane < 16) red[mt][n] = sacc;
    }
    __syncthreads();
    if (tid < SPW)
        out[bseq + tid] = red[0][tid] + red[1][tid] + red[2][tid] + red[3][tid] + fcb0;
}

extern "C" void kernel_launch(void* const* d_in, const int* in_sizes, int n_in,
                              void* d_out, int out_size, void* d_ws, size_t ws_size,
                              hipStream_t stream) {
    const float* x    = (const float*)d_in[0];
    const float* Wih0 = (const float*)d_in[1];
    const float* Whh0 = (const float*)d_in[2];
    const float* bih0 = (const float*)d_in[3];
    const float* bhh0 = (const float*)d_in[4];
    const float* Wih1 = (const float*)d_in[5];
    const float* Whh1 = (const float*)d_in[6];
    const float* bih1 = (const float*)d_in[7];
    const float* bhh1 = (const float*)d_in[8];
    const float* fcw  = (const float*)d_in[9];
    const float* fcb  = (const float*)d_in[10];
    float* out = (float*)d_out;

    if (d_ws != nullptr && ws_size >= WS_NEEDED) {
        // zero producer/consumer flags each launch (graph-replay safe; ring
        // data is gated by the flags so it needs no reset)
        hipMemsetAsync(d_ws, 0, NPAIR * FLAG_STRIDE, stream);
        rnn2_decoup<<<dim3(2 * NPAIR), dim3(256), 0, stream>>>(
            x, Wih0, Whh0, bih0, bhh0, Wih1, Whh1, bih1, bhh1, fcw, fcb, out, d_ws);
    } else {
        rnn2_cf<<<dim3(NBLK), dim3(512), 0, stream>>>(
            x, Wih0, Whh0, bih0, bhh0, Wih1, Whh1, bih1, bhh1, fcw, fcb, out);
    }
}

// Round 10
// 238.800 us; speedup vs baseline: 1.2105x; 1.2105x over previous
//
#include <hip/hip_runtime.h>

#define T_STEPS 512
#define BATCH   2048
#define HID     64
#define IN0     8
#define SPW     16                // seqs per block (MFMA N dim)
#define NBLK    (BATCH / SPW)     // 128 blocks x 4 waves (256 thr)
#define SS      8                 // x-prefetch depth
#define NSS     (T_STEPS / SS)

typedef _Float16 h2 __attribute__((ext_vector_type(2)));
typedef _Float16 h8 __attribute__((ext_vector_type(8)));
typedef float    f4 __attribute__((ext_vector_type(4)));

#define MFMA(a, b, c) __builtin_amdgcn_mfma_f32_16x16x32_f16((a), (b), (c), 0, 0, 0)

union F8 { h8 v; h2 p[4]; };

__device__ __forceinline__ h2 pkrtz(float a, float b) {
    return __builtin_bit_cast(h2, __builtin_amdgcn_cvt_pkrtz(a, b));
}

// tanh(x) = 1 - 2/(exp(2x)+1); saturates correctly at +/-inf.
__device__ __forceinline__ float tanh_fast(float x) {
    float e = __builtin_amdgcn_exp2f(x * 2.885390081777927f);
    return 1.0f - 2.0f * __builtin_amdgcn_rcpf(e + 1.0f);
}

__device__ __forceinline__ h8 load_frag_f16(const float* Wrow) {
    const float4* p = (const float4*)Wrow;
    float4 a = p[0], b = p[1];
    F8 f; f.p[0] = pkrtz(a.x, a.y); f.p[1] = pkrtz(a.z, a.w);
          f.p[2] = pkrtz(b.x, b.y); f.p[3] = pkrtz(b.z, b.w);
    return f.v;
}

// Barrier draining ONLY lgkmcnt (LDS); x-prefetch globals stay in flight.
// lgkmcnt(0) also retires this step's stable-buffer READS before any wave
// can cross and overwrite them next step (race-safety for the C-waves).
#define LDS_BARRIER() asm volatile("s_waitcnt lgkmcnt(0)\n\ts_barrier" ::: "memory")

// sigma row permutation (verified R2): C slot (mt, 4q+r) holds actual H row
//   32*(mt>>1) + 4*(mt&1) + 8*q + r,
// so pack2(th[2kt], th[2kt+1]) IS the complete B-operand for k-tile kt.
// Half-split: wave owns m-tiles {2hf, 2hf+1} -> its pack output = the full
// k-tile-hf B fragment. Exchange = 1 ds_write_b128 + 1 ds_read_b128 per step.
__global__ __launch_bounds__(256, 1)
void rnn2_half(const float* __restrict__ x,
               const float* __restrict__ Wih0, const float* __restrict__ Whh0,
               const float* __restrict__ bih0, const float* __restrict__ bhh0,
               const float* __restrict__ Wih1, const float* __restrict__ Whh1,
               const float* __restrict__ bih1, const float* __restrict__ bhh1,
               const float* __restrict__ fcw,  const float* __restrict__ fcb,
               float* __restrict__ out) {
    const int tid  = threadIdx.x;
    const int w    = tid >> 6;     // 0,1 = L0 halves; 2,3 = L1 halves
    const int lane = tid & 63;
    const int n    = lane & 15;    // seq column / A-row-slot
    const int q    = lane >> 4;
    const int bseq = blockIdx.x * SPW;
    const bool isL0 = (w < 2);
    const int hf   = isL0 ? w : (w - 2);   // owned k-tile
    const int mt0  = 2 * hf;               // owned m-tiles: mt0, mt0+1

    // [bf][half][lane] complete B-fragments; 16B/lane linear (conflict-free,
    // R3-pattern measured 0 conflicts). 8.2 KB total.
    __shared__ __align__(16) h8 X0[2][2][64];
    __shared__ __align__(16) h8 X1[2][2][64];
    __shared__ float red[2][SPW];

    // zero-init: H0(-1)=H1(-1)=0 reads at t=0/1 come from these
    {
        h8 z = {};
        X0[w >> 1][w & 1][lane] = z;
        X1[w >> 1][w & 1][lane] = z;
    }
    __syncthreads();

    const f4 zero = {0.f, 0.f, 0.f, 0.f};
    const h2 z2 = pkrtz(0.f, 0.f);
    const float fcb0 = fcb[0];

    if (isL0) {
        // ---------------- layer-0 half-wave ----------------
        h8 wh[2][2], wi[2];        // [l][kt]; l: local m-tile
        f4 bias[2];
        #pragma unroll
        for (int l = 0; l < 2; ++l) {
            const int mt = mt0 + l;
            const int ar = 32 * (mt >> 1) + 4 * (mt & 1) + 8 * (n >> 2) + (n & 3);
            #pragma unroll
            for (int kt = 0; kt < 2; ++kt)
                wh[l][kt] = load_frag_f16(Whh0 + ar * HID + 32 * kt + 8 * q);
            const float2 ww = *(const float2*)(Wih0 + ar * IN0 + 2 * q);
            F8 f; f.p[0] = pkrtz(ww.x, ww.y); f.p[1] = z2; f.p[2] = z2; f.p[3] = z2;
            wi[l] = f.v;
            #pragma unroll
            for (int r = 0; r < 4; ++r) {
                const int cr = 32 * (mt >> 1) + 4 * (mt & 1) + 8 * q + r;
                bias[l][r] = bih0[cr] + bhh0[cr];
            }
        }
        const float* xrow = x + ((size_t)(bseq + n)) * T_STEPS * IN0 + 2 * q;
        float2 xb[SS];
        f4 cpart[2];               // a0x(t) + wh[l][hf]@ownhalf(t-1)
        {
            const float2 x0 = *(const float2*)xrow;
            F8 xf; xf.p[0] = pkrtz(x0.x, x0.y); xf.p[1] = z2; xf.p[2] = z2; xf.p[3] = z2;
            #pragma unroll
            for (int l = 0; l < 2; ++l) cpart[l] = MFMA(wi[l], xf.v, bias[l]);
            #pragma unroll
            for (int i = 0; i < SS; ++i) {
                int tn = i + 1; if (tn > T_STEPS - 1) tn = T_STEPS - 1;
                xb[i] = *(const float2*)(xrow + tn * IN0);
            }
        }
        for (int s = 0; s < NSS; ++s) {
            #pragma unroll
            for (int i = 0; i < SS; ++i) {
                const int t = SS * s + i;
                const int bf = t & 1;
                // chain: read sibling half of H0(t-1), finish the MFMA
                const h8 other = X0[bf ^ 1][hf ^ 1][lane];
                f4 c0 = MFMA(wh[0][hf ^ 1], other, cpart[0]);
                f4 c1 = MFMA(wh[1][hf ^ 1], other, cpart[1]);
                F8 pk;
                pk.p[0] = pkrtz(tanh_fast(c0[0]), tanh_fast(c0[1]));
                pk.p[1] = pkrtz(tanh_fast(c0[2]), tanh_fast(c0[3]));
                pk.p[2] = pkrtz(tanh_fast(c1[0]), tanh_fast(c1[1]));
                pk.p[3] = pkrtz(tanh_fast(c1[2]), tanh_fast(c1[3]));
                const h8 own = pk.v;           // full k-tile-hf B-frag of H0(t)
                X0[bf][hf][lane] = own;
                // pre-issue next step (off the post-barrier chain):
                F8 xf; xf.p[0] = pkrtz(xb[i].x, xb[i].y);
                xf.p[1] = z2; xf.p[2] = z2; xf.p[3] = z2;
                cpart[0] = MFMA(wh[0][hf], own, MFMA(wi[0], xf.v, bias[0]));
                cpart[1] = MFMA(wh[1][hf], own, MFMA(wi[1], xf.v, bias[1]));
                int tn = t + 1 + SS; if (tn > T_STEPS - 1) tn = T_STEPS - 1;
                xb[i] = *(const float2*)(xrow + tn * IN0);
                LDS_BARRIER();
            }
        }
    } else {
        // ---------------- layer-1 half-wave ----------------
        // step t computes H1(t-1); ALL inputs are stable bf^1 buffers.
        h8 wa[2][2], wb[2][2];
        f4 bias[2], fcv[2];
        #pragma unroll
        for (int l = 0; l < 2; ++l) {
            const int mt = mt0 + l;
            const int ar = 32 * (mt >> 1) + 4 * (mt & 1) + 8 * (n >> 2) + (n & 3);
            #pragma unroll
            for (int kt = 0; kt < 2; ++kt) {
                wa[l][kt] = load_frag_f16(Wih1 + ar * HID + 32 * kt + 8 * q);
                wb[l][kt] = load_frag_f16(Whh1 + ar * HID + 32 * kt + 8 * q);
            }
            #pragma unroll
            for (int r = 0; r < 4; ++r) {
                const int cr = 32 * (mt >> 1) + 4 * (mt & 1) + 8 * q + r;
                bias[l][r] = bih1[cr] + bhh1[cr];
                fcv[l][r]  = fcw[cr];
            }
        }
        h8 own1 = {};              // own H1 half (t-2 at step top); H1(-1)=0
        for (int s = 0; s < NSS; ++s) {
            #pragma unroll
            for (int i = 0; i < SS; ++i) {
                const int t = SS * s + i;
                const int bf = t & 1;
                const h8 h00 = X0[bf ^ 1][0][lane];      // H0(t-1) both halves
                const h8 h01 = X0[bf ^ 1][1][lane];
                const h8 h1o = X1[bf ^ 1][hf ^ 1][lane]; // sibling H1(t-2)
                f4 e0 = MFMA(wa[0][0], h00, bias[0]);
                e0    = MFMA(wa[0][1], h01, e0);
                f4 g0 = MFMA(wb[0][hf ^ 1], h1o, zero);
                g0    = MFMA(wb[0][hf], own1, g0);
                f4 e1 = MFMA(wa[1][0], h00, bias[1]);
                e1    = MFMA(wa[1][1], h01, e1);
                f4 g1 = MFMA(wb[1][hf ^ 1], h1o, zero);
                g1    = MFMA(wb[1][hf], own1, g1);
                const f4 d0 = e0 + g0, d1 = e1 + g1;
                F8 pk;
                pk.p[0] = pkrtz(tanh_fast(d0[0]), tanh_fast(d0[1]));
                pk.p[1] = pkrtz(tanh_fast(d0[2]), tanh_fast(d0[3]));
                pk.p[2] = pkrtz(tanh_fast(d1[0]), tanh_fast(d1[1]));
                pk.p[3] = pkrtz(tanh_fast(d1[2]), tanh_fast(d1[3]));
                h8 newown = pk.v;
                if (t == 0) { h8 z = {}; newown = z; }    // true H1(-1)=0
                own1 = newown;
                X1[bf][hf][lane] = own1;
                LDS_BARRIER();
            }
        }
        // epilogue: H1(511) from H0(511)=X0[1], H1(510)={own1, X1[1][hf^1]}
        {
            const h8 h00 = X0[1][0][lane];
            const h8 h01 = X0[1][1][lane];
            const h8 h1o = X1[1][hf ^ 1][lane];
            f4 e0 = MFMA(wa[0][0], h00, bias[0]);
            e0    = MFMA(wa[0][1], h01, e0);
            f4 g0 = MFMA(wb[0][hf ^ 1], h1o, zero);
            g0    = MFMA(wb[0][hf], own1, g0);
            f4 e1 = MFMA(wa[1][0], h00, bias[1]);
            e1    = MFMA(wa[1][1], h01, e1);
            f4 g1 = MFMA(wb[1][hf ^ 1], h1o, zero);
            g1    = MFMA(wb[1][hf], own1, g1);
            const f4 d0 = e0 + g0, d1 = e1 + g1;
            float sacc = 0.f;
            #pragma unroll
            for (int r = 0; r < 4; ++r) {
                sacc += fcv[0][r] * tanh_fast(d0[r]);
                sacc += fcv[1][r] * tanh_fast(d1[r]);
            }
            sacc += __shfl_xor(sacc, 16, 64);
            sacc += __shfl_xor(sacc, 32, 64);
            if (lane < 16) red[hf][n] = sacc;   // q==0 lanes
        }
    }

    __syncthreads();
    if (tid < SPW)
        out[bseq + tid] = red[0][tid] + red[1][tid] + fcb0;
}

extern "C" void kernel_launch(void* const* d_in, const int* in_sizes, int n_in,
                              void* d_out, int out_size, void* d_ws, size_t ws_size,
                              hipStream_t stream) {
    const float* x    = (const float*)d_in[0];
    const float* Wih0 = (const float*)d_in[1];
    const float* Whh0 = (const float*)d_in[2];
    const float* bih0 = (const float*)d_in[3];
    const float* bhh0 = (const float*)d_in[4];
    const float* Wih1 = (const float*)d_in[5];
    const float* Whh1 = (const float*)d_in[6];
    const float* bih1 = (const float*)d_in[7];
    const float* bhh1 = (const float*)d_in[8];
    const float* fcw  = (const float*)d_in[9];
    const float* fcb  = (const float*)d_in[10];
    float* out = (float*)d_out;

    rnn2_half<<<dim3(NBLK), dim3(256), 0, stream>>>(
        x, Wih0, Whh0, bih0, bhh0, Wih1, Whh1, bih1, bhh1, fcw, fcb, out);
}

// Round 11
// 232.903 us; speedup vs baseline: 1.2411x; 1.0253x over previous
//
#include <hip/hip_runtime.h>

#define T_STEPS 512
#define BATCH   2048
#define HID     64
#define IN0     8
#define SPW     16                // seqs per block (MFMA N dim)
#define NBLK    (BATCH / SPW)     // 128 blocks x 4 waves (256 thr)
#define SS      8                 // x-prefetch depth
#define NSS     (T_STEPS / SS)

typedef _Float16 h2 __attribute__((ext_vector_type(2)));
typedef _Float16 h8 __attribute__((ext_vector_type(8)));
typedef float    f4 __attribute__((ext_vector_type(4)));

#define MFMA(a, b, c) __builtin_amdgcn_mfma_f32_16x16x32_f16((a), (b), (c), 0, 0, 0)

union F8 { h8 v; h2 p[4]; };

__device__ __forceinline__ h2 pkrtz(float a, float b) {
    return __builtin_bit_cast(h2, __builtin_amdgcn_cvt_pkrtz(a, b));
}

// tanh(x) = 1 - 2/(exp(2x)+1); saturates correctly at +/-inf.
__device__ __forceinline__ float tanh_fast(float x) {
    float e = __builtin_amdgcn_exp2f(x * 2.885390081777927f);
    return 1.0f - 2.0f * __builtin_amdgcn_rcpf(e + 1.0f);
}

__device__ __forceinline__ h8 load_frag_f16(const float* Wrow) {
    const float4* p = (const float4*)Wrow;
    float4 a = p[0], b = p[1];
    F8 f; f.p[0] = pkrtz(a.x, a.y); f.p[1] = pkrtz(a.z, a.w);
          f.p[2] = pkrtz(b.x, b.y); f.p[3] = pkrtz(b.z, b.w);
    return f.v;
}

// Barrier draining ONLY lgkmcnt (LDS); x-prefetch globals stay in flight.
// lgkmcnt(0) also retires this step's stable-buffer READS before any wave
// can cross and overwrite them next step (double-buffer race-safety).
// NOTE: asm volatile is a scheduling fence — source order around it is
// execution order. Keep the write as the LAST op before the barrier and
// put all off-chain work in the post-barrier ds_read shadow.
#define LDS_BARRIER() asm volatile("s_waitcnt lgkmcnt(0)\n\ts_barrier" ::: "memory")

// sigma row permutation (verified R2/R9): C slot (mt, 4q+r) holds actual H
// row 32*(mt>>1) + 4*(mt&1) + 8*q + r, so a wave owning m-tiles {2hf,2hf+1}
// packs its 8 C values into the COMPLETE k-tile-hf B operand. Exchange =
// 1 ds_write_b128 + 1 ds_read_b128 per step (conflict-free, measured R9).
__global__ __launch_bounds__(256, 1)
void rnn2_shadow(const float* __restrict__ x,
                 const float* __restrict__ Wih0, const float* __restrict__ Whh0,
                 const float* __restrict__ bih0, const float* __restrict__ bhh0,
                 const float* __restrict__ Wih1, const float* __restrict__ Whh1,
                 const float* __restrict__ bih1, const float* __restrict__ bhh1,
                 const float* __restrict__ fcw,  const float* __restrict__ fcb,
                 float* __restrict__ out) {
    const int tid  = threadIdx.x;
    const int w    = tid >> 6;     // 0,1 = L0 halves; 2,3 = L1 halves
    const int lane = tid & 63;
    const int n    = lane & 15;    // seq column / A-row-slot
    const int q    = lane >> 4;
    const int bseq = blockIdx.x * SPW;
    const bool isL0 = (w < 2);
    const int hf   = isL0 ? w : (w - 2);   // owned k-tile
    const int mt0  = 2 * hf;               // owned m-tiles: mt0, mt0+1

    // [bf][half][lane] complete B-fragments; 16B/lane linear (0 conflicts,
    // measured R9). 8.2 KB total.
    __shared__ __align__(16) h8 X0[2][2][64];
    __shared__ __align__(16) h8 X1[2][2][64];
    __shared__ float red[2][SPW];

    // zero-init: H0(-1)=H1(-1)=0 reads at t=0/1 come from these
    {
        h8 z = {};
        X0[w >> 1][w & 1][lane] = z;
        X1[w >> 1][w & 1][lane] = z;
    }
    __syncthreads();

    const f4 zero = {0.f, 0.f, 0.f, 0.f};
    const h2 z2 = pkrtz(0.f, 0.f);
    const float fcb0 = fcb[0];

    if (isL0) {
        // ---------------- layer-0 half-wave ----------------
        h8 wh[2][2], wi[2];        // [l][kt]; l: local m-tile
        f4 bias[2];
        #pragma unroll
        for (int l = 0; l < 2; ++l) {
            const int mt = mt0 + l;
            const int ar = 32 * (mt >> 1) + 4 * (mt & 1) + 8 * (n >> 2) + (n & 3);
            #pragma unroll
            for (int kt = 0; kt < 2; ++kt)
                wh[l][kt] = load_frag_f16(Whh0 + ar * HID + 32 * kt + 8 * q);
            const float2 ww = *(const float2*)(Wih0 + ar * IN0 + 2 * q);
            F8 f; f.p[0] = pkrtz(ww.x, ww.y); f.p[1] = z2; f.p[2] = z2; f.p[3] = z2;
            wi[l] = f.v;
            #pragma unroll
            for (int r = 0; r < 4; ++r) {
                const int cr = 32 * (mt >> 1) + 4 * (mt & 1) + 8 * q + r;
                bias[l][r] = bih0[cr] + bhh0[cr];
            }
        }
        const float* xrow = x + ((size_t)(bseq + n)) * T_STEPS * IN0 + 2 * q;
        float2 xb[SS];             // xb[t&7] = x(t) at top of step t
        #pragma unroll
        for (int i = 0; i < SS; ++i)
            xb[i] = *(const float2*)(xrow + i * IN0);

        h8 own = {};               // own half of H0(t-1); H0(-1)=0
        for (int s = 0; s < NSS; ++s) {
            #pragma unroll
            for (int i = 0; i < SS; ++i) {
                const int t = SS * s + i;
                const int bf = t & 1;
                // (1) chain read FIRST: sibling half of H0(t-1)
                const h8 other = X0[bf ^ 1][hf ^ 1][lane];
                // (2) read shadow: cpart(t) = bias + Wih@x(t) + Whh[own]@own(t-1)
                F8 xf; xf.p[0] = pkrtz(xb[i].x, xb[i].y);
                xf.p[1] = z2; xf.p[2] = z2; xf.p[3] = z2;
                f4 cp0 = MFMA(wi[0], xf.v, bias[0]);
                f4 cp1 = MFMA(wi[1], xf.v, bias[1]);
                cp0 = MFMA(wh[0][hf], own, cp0);
                cp1 = MFMA(wh[1][hf], own, cp1);
                // x refill (lands in 8 steps; off-chain issue)
                int tn = t + SS; if (tn > T_STEPS - 1) tn = T_STEPS - 1;
                xb[i] = *(const float2*)(xrow + tn * IN0);
                // (3) chain: finish MFMA, tanh, pack, publish, barrier
                f4 c0 = MFMA(wh[0][hf ^ 1], other, cp0);
                f4 c1 = MFMA(wh[1][hf ^ 1], other, cp1);
                F8 pk;
                pk.p[0] = pkrtz(tanh_fast(c0[0]), tanh_fast(c0[1]));
                pk.p[1] = pkrtz(tanh_fast(c0[2]), tanh_fast(c0[3]));
                pk.p[2] = pkrtz(tanh_fast(c1[0]), tanh_fast(c1[1]));
                pk.p[3] = pkrtz(tanh_fast(c1[2]), tanh_fast(c1[3]));
                own = pk.v;                    // full k-tile-hf B-frag of H0(t)
                X0[bf][hf][lane] = own;
                LDS_BARRIER();
            }
        }
    } else {
        // ---------------- layer-1 half-wave ----------------
        // step t computes H1(t-1); ALL inputs are stable bf^1 buffers.
        h8 wa[2][2], wb[2][2];
        f4 bias[2], fcv[2];
        #pragma unroll
        for (int l = 0; l < 2; ++l) {
            const int mt = mt0 + l;
            const int ar = 32 * (mt >> 1) + 4 * (mt & 1) + 8 * (n >> 2) + (n & 3);
            #pragma unroll
            for (int kt = 0; kt < 2; ++kt) {
                wa[l][kt] = load_frag_f16(Wih1 + ar * HID + 32 * kt + 8 * q);
                wb[l][kt] = load_frag_f16(Whh1 + ar * HID + 32 * kt + 8 * q);
            }
            #pragma unroll
            for (int r = 0; r < 4; ++r) {
                const int cr = 32 * (mt >> 1) + 4 * (mt & 1) + 8 * q + r;
                bias[l][r] = bih1[cr] + bhh1[cr];
                fcv[l][r]  = fcw[cr];
            }
        }
        h8 own1 = {};              // own H1 half (t-2 at step top); H1(-1)=0
        for (int s = 0; s < NSS; ++s) {
            #pragma unroll
            for (int i = 0; i < SS; ++i) {
                const int t = SS * s + i;
                const int bf = t & 1;
                // (1) chain reads FIRST
                const h8 h00 = X0[bf ^ 1][0][lane];      // H0(t-1) both halves
                const h8 h01 = X0[bf ^ 1][1][lane];
                const h8 h1o = X1[bf ^ 1][hf ^ 1][lane]; // sibling H1(t-2)
                // (2) read shadow: own-half H1 partials (own1 in registers)
                f4 g0 = MFMA(wb[0][hf], own1, zero);
                f4 g1 = MFMA(wb[1][hf], own1, zero);
                // (3) chain when reads land
                f4 e0 = MFMA(wa[0][0], h00, bias[0]);
                f4 e1 = MFMA(wa[1][0], h00, bias[1]);
                e0 = MFMA(wa[0][1], h01, e0);
                e1 = MFMA(wa[1][1], h01, e1);
                g0 = MFMA(wb[0][hf ^ 1], h1o, g0);
                g1 = MFMA(wb[1][hf ^ 1], h1o, g1);
                const f4 d0 = e0 + g0, d1 = e1 + g1;
                F8 pk;
                pk.p[0] = pkrtz(tanh_fast(d0[0]), tanh_fast(d0[1]));
                pk.p[1] = pkrtz(tanh_fast(d0[2]), tanh_fast(d0[3]));
                pk.p[2] = pkrtz(tanh_fast(d1[0]), tanh_fast(d1[1]));
                pk.p[3] = pkrtz(tanh_fast(d1[2]), tanh_fast(d1[3]));
                h8 newown = pk.v;
                if (t == 0) { h8 z = {}; newown = z; }    // true H1(-1)=0
                own1 = newown;
                X1[bf][hf][lane] = own1;
                LDS_BARRIER();
            }
        }
        // epilogue: H1(511) from H0(511)=X0[1], H1(510)={own1, X1[1][hf^1]}
        {
            const h8 h00 = X0[1][0][lane];
            const h8 h01 = X0[1][1][lane];
            const h8 h1o = X1[1][hf ^ 1][lane];
            f4 e0 = MFMA(wa[0][0], h00, bias[0]);
            e0    = MFMA(wa[0][1], h01, e0);
            f4 g0 = MFMA(wb[0][hf ^ 1], h1o, zero);
            g0    = MFMA(wb[0][hf], own1, g0);
            f4 e1 = MFMA(wa[1][0], h00, bias[1]);
            e1    = MFMA(wa[1][1], h01, e1);
            f4 g1 = MFMA(wb[1][hf ^ 1], h1o, zero);
            g1    = MFMA(wb[1][hf], own1, g1);
            const f4 d0 = e0 + g0, d1 = e1 + g1;
            float sacc = 0.f;
            #pragma unroll
            for (int r = 0; r < 4; ++r) {
                sacc += fcv[0][r] * tanh_fast(d0[r]);
                sacc += fcv[1][r] * tanh_fast(d1[r]);
            }
            sacc += __shfl_xor(sacc, 16, 64);
            sacc += __shfl_xor(sacc, 32, 64);
            if (lane < 16) red[hf][n] = sacc;   // q==0 lanes
        }
    }

    __syncthreads();
    if (tid < SPW)
        out[bseq + tid] = red[0][tid] + red[1][tid] + fcb0;
}

extern "C" void kernel_launch(void* const* d_in, const int* in_sizes, int n_in,
                              void* d_out, int out_size, void* d_ws, size_t ws_size,
                              hipStream_t stream) {
    const float* x    = (const float*)d_in[0];
    const float* Wih0 = (const float*)d_in[1];
    const float* Whh0 = (const float*)d_in[2];
    const float* bih0 = (const float*)d_in[3];
    const float* bhh0 = (const float*)d_in[4];
    const float* Wih1 = (const float*)d_in[5];
    const float* Whh1 = (const float*)d_in[6];
    const float* bih1 = (const float*)d_in[7];
    const float* bhh1 = (const float*)d_in[8];
    const float* fcw  = (const float*)d_in[9];
    const float* fcb  = (const float*)d_in[10];
    float* out = (float*)d_out;

    rnn2_shadow<<<dim3(NBLK), dim3(256), 0, stream>>>(
        x, Wih0, Whh0, bih0, bhh0, Wih1, Whh1, bih1, bhh1, fcw, fcb, out);
}